// Round 1
// baseline (452.052 us; speedup 1.0000x reference)
//
#include <hip/hip_runtime.h>
#include <hip/hip_bf16.h>
#include <cstdint>
#include <math.h>

// ---------------------------------------------------------------------------
// GMemLinear: out = (x @ W^T) + bias, W = jax.random.normal(key(seed), [N,K], f64)
// Plan: (1) regenerate W on device via threefry2x32 (partitionable counters)
//       + erfinv, store bf16 in ws; (2) cast x f32->bf16 in ws; (3) bf16 MFMA
//       GEMM (m97 128^2 structure, global_load_lds w=16) with bias epilogue.
// ---------------------------------------------------------------------------

typedef __bf16  bf16x8 __attribute__((ext_vector_type(8)));
typedef float   f32x4  __attribute__((ext_vector_type(4)));
typedef unsigned short u16x8 __attribute__((ext_vector_type(8)));

__device__ __forceinline__ unsigned short f2bf_rne(float f) {
  uint32_t x = __float_as_uint(f);
  uint32_t r = (x + 0x7FFFu + ((x >> 16) & 1u)) >> 16;
  return (unsigned short)r;
}

// Threefry-2x32, 20 rounds (Random123 / JAX).
__device__ __forceinline__ void threefry2x32(uint32_t k0, uint32_t k1,
                                             uint32_t x0, uint32_t x1,
                                             uint32_t& o0, uint32_t& o1) {
  uint32_t ks0 = k0, ks1 = k1, ks2 = k0 ^ k1 ^ 0x1BD11BDAu;
  uint32_t ks[3] = {ks0, ks1, ks2};
  x0 += ks0; x1 += ks1;
  const uint32_t rot0[4] = {13u, 15u, 26u, 6u};
  const uint32_t rot1[4] = {17u, 29u, 16u, 24u};
#pragma unroll
  for (int i = 0; i < 5; ++i) {
    const uint32_t* r = (i & 1) ? rot1 : rot0;
#pragma unroll
    for (int j = 0; j < 4; ++j) {
      x0 += x1;
      x1 = (x1 << r[j]) | (x1 >> (32u - r[j]));
      x1 ^= x0;
    }
    x0 += ks[(i + 1) % 3];
    x1 += ks[(i + 2) % 3] + (uint32_t)(i + 1);
  }
  o0 = x0; o1 = x1;
}

// erfinv: Giles fp32 (w < 15.5, within its design range) + asymptotic double
// tail for the ultra-rare |u| -> 1 samples (abs err ~5e-3, plenty vs thr 7.2).
__device__ __forceinline__ double erfinv_mixed(double u) {
  double au = fabs(u);
  double t  = (1.0 - au) * (1.0 + au);     // 1 - u^2, >= ~2^-52
  float  wf = -logf((float)t);
  if (wf < 15.5f) {
    float w, p;
    if (wf < 5.0f) {
      w = wf - 2.5f;
      p = 2.81022636e-08f;
      p = 3.43273939e-07f + p * w;
      p = -3.5233877e-06f + p * w;
      p = -4.39150654e-06f + p * w;
      p = 0.00021858087f + p * w;
      p = -0.00125372503f + p * w;
      p = -0.00417768164f + p * w;
      p = 0.246640727f + p * w;
      p = 1.50140941f + p * w;
    } else {
      w = sqrtf(wf) - 3.0f;
      p = -0.000200214257f;
      p = 0.000100950558f + p * w;
      p = 0.00134934322f + p * w;
      p = -0.00367342844f + p * w;
      p = 0.00573950773f + p * w;
      p = -0.0076224613f + p * w;
      p = 0.00943887047f + p * w;
      p = 1.00167406f + p * w;
      p = 2.83297682f + p * w;
    }
    return (double)(p * (float)u);
  } else {
    // deep tail: solve x^2 + ln x + ln sqrt(pi) = -ln(1-|u|)
    double L = -log(1.0 - au);             // 1-au exact here (Sterbenz)
    double r = sqrt(L);
    r = sqrt(L - log(r) - 0.5723649429247001);
    r = sqrt(L - log(r) - 0.5723649429247001);
    return (u < 0.0) ? -r : r;
  }
}

// ---------------------------------------------------------------------------
// Kernel 1: regenerate W [N=4096][K=4096] as bf16 into ws.
// JAX partitionable threefry: element e -> ctr (hi=0, lo=e), 64 bits =
// (o0<<32)|o1; double in [0,1) = bitcast((bits>>12)|0x3FF0...) - 1;
// u = f*2.0 + (-(1-2^-53)); w = sqrt(2)*erfinv(u).
// ---------------------------------------------------------------------------
__global__ void genw_kernel(unsigned short* __restrict__ W,
                            const int* __restrict__ seedp, int total) {
  const uint32_t k1 = (uint32_t)seedp[0];
  const uint32_t k0 = 0u;
  const double DLO = -0x1.fffffffffffffp-1;   // -(1 - 2^-53)
  const int nq = total >> 2;
  const int stride = (int)(gridDim.x * blockDim.x);
  for (int q = (int)(blockIdx.x * blockDim.x + threadIdx.x); q < nq; q += stride) {
    ushort4 outv;
    unsigned short tmp[4];
#pragma unroll
    for (int j = 0; j < 4; ++j) {
      uint32_t e = ((uint32_t)q << 2) + (uint32_t)j;
      uint32_t o0, o1;
      threefry2x32(k0, k1, 0u, e, o0, o1);
      uint64_t bits = ((uint64_t)o0 << 32) | (uint64_t)o1;
      uint64_t fb = (bits >> 12) | 0x3FF0000000000000ull;
      union { uint64_t u; double d; } cv; cv.u = fb;
      double f = cv.d - 1.0;
      double u = f * 2.0 + DLO;
      u = fmax(u, DLO);
      double x = erfinv_mixed(u);
      float wv = (float)(1.4142135623730951 * x);
      tmp[j] = f2bf_rne(wv);
    }
    outv.x = tmp[0]; outv.y = tmp[1]; outv.z = tmp[2]; outv.w = tmp[3];
    *(ushort4*)(W + ((size_t)q << 2)) = outv;
  }
}

// ---------------------------------------------------------------------------
// Kernel 2: cast x f32 -> bf16 (vectorized 8/thread).
// ---------------------------------------------------------------------------
__global__ void castx_kernel(const float* __restrict__ X,
                             unsigned short* __restrict__ Y, int n) {
  const int n8 = n >> 3;
  const int stride = (int)(gridDim.x * blockDim.x);
  for (int q = (int)(blockIdx.x * blockDim.x + threadIdx.x); q < n8; q += stride) {
    const float4* p = (const float4*)(X + ((size_t)q << 3));
    float4 a = p[0], b = p[1];
    u16x8 o;
    o[0] = f2bf_rne(a.x); o[1] = f2bf_rne(a.y);
    o[2] = f2bf_rne(a.z); o[3] = f2bf_rne(a.w);
    o[4] = f2bf_rne(b.x); o[5] = f2bf_rne(b.y);
    o[6] = f2bf_rne(b.z); o[7] = f2bf_rne(b.w);
    *(u16x8*)(Y + ((size_t)q << 3)) = o;
  }
}

// ---------------------------------------------------------------------------
// Kernel 3: bf16 GEMM C[M][N] = A[M][K] * B[N][K]^T + bias, m97 structure:
// 128x128 tile, BK=32, 4 waves (2x2, 64x64 each), 16x16x32 MFMA,
// global_load_lds width 16, XCD-bijective blockIdx swizzle.
// ---------------------------------------------------------------------------
#define BM 128
#define BN 128
#define BKK 32

__device__ __forceinline__ void gload_lds16(const void* g, void* l) {
  __builtin_amdgcn_global_load_lds(
      (const __attribute__((address_space(1))) unsigned int*)g,
      (__attribute__((address_space(3))) unsigned int*)l, 16, 0, 0);
}

__global__ __launch_bounds__(256) void gemm_bt_bias(
    const __hip_bfloat16* __restrict__ A,   // [M][K] bf16
    const __hip_bfloat16* __restrict__ B,   // [N][K] bf16 (W)
    const float* __restrict__ bias,         // [N]
    float* __restrict__ C,                  // [M][N] f32
    int M, int N, int K) {
  __shared__ __align__(16) __hip_bfloat16 As[BM][BKK];
  __shared__ __align__(16) __hip_bfloat16 Bs[BN][BKK];

  // XCD-aware bijective swizzle (nwg % 8 == 0 for this shape)
  const int nwg = (int)gridDim.x;
  const int bid = (int)blockIdx.x;
  int wg = bid;
  if ((nwg & 7) == 0) wg = (bid & 7) * (nwg >> 3) + (bid >> 3);
  const int ntn = N / BN;
  const int tm = wg / ntn, tn = wg % ntn;

  const int tid  = (int)threadIdx.x;
  const int wid  = tid >> 6;
  const int lane = tid & 63;
  const int wr = wid >> 1, wc = wid & 1;     // wave grid 2x2 of 64x64
  const int l15 = lane & 15;
  const int kq  = lane >> 4;                 // 0..3

  // staging lane coords: 16B per lane, 4 lanes per 64B row, 16 rows per issue
  const int srow = lane >> 2;
  const int scol = (lane & 3) * 16;          // bytes

  f32x4 acc[4][4];
#pragma unroll
  for (int i = 0; i < 4; ++i)
#pragma unroll
    for (int j = 0; j < 4; ++j) acc[i][j] = (f32x4){0.f, 0.f, 0.f, 0.f};

  const char* Ab = (const char*)A;
  const char* Bb = (const char*)B;

  for (int kt = 0; kt < K; kt += BKK) {
#pragma unroll
    for (int q = 0; q < 2; ++q) {
      const int r = wid * 32 + q * 16;       // wave-uniform
      const char* ga = Ab + ((size_t)(tm * BM + r + srow) * K + kt) * 2 + scol;
      gload_lds16(ga, (void*)&As[r][0]);
      const char* gb = Bb + ((size_t)(tn * BN + r + srow) * K + kt) * 2 + scol;
      gload_lds16(gb, (void*)&Bs[r][0]);
    }
    __syncthreads();                          // drains vmcnt before barrier

    bf16x8 a[4];
#pragma unroll
    for (int mi = 0; mi < 4; ++mi)
      a[mi] = *(const bf16x8*)&As[wr * 64 + mi * 16 + l15][kq * 8];
#pragma unroll
    for (int ni = 0; ni < 4; ++ni) {
      bf16x8 b = *(const bf16x8*)&Bs[wc * 64 + ni * 16 + l15][kq * 8];
#pragma unroll
      for (int mi = 0; mi < 4; ++mi)
        acc[mi][ni] = __builtin_amdgcn_mfma_f32_16x16x32_bf16(a[mi], b, acc[mi][ni], 0, 0, 0);
    }
    __syncthreads();
  }

  // epilogue: C = acc + bias ; C/D layout: col = lane&15, row = (lane>>4)*4+j
#pragma unroll
  for (int ni = 0; ni < 4; ++ni) {
    const int col = tn * BN + wc * 64 + ni * 16 + l15;
    const float bv = bias[col];
#pragma unroll
    for (int mi = 0; mi < 4; ++mi) {
      const int row0 = tm * BM + wr * 64 + mi * 16 + kq * 4;
      f32x4 v = acc[mi][ni];
#pragma unroll
      for (int j = 0; j < 4; ++j)
        C[(size_t)(row0 + j) * N + col] = v[j] + bv;
    }
  }
}

// ---------------------------------------------------------------------------
extern "C" void kernel_launch(void* const* d_in, const int* in_sizes, int n_in,
                              void* d_out, int out_size, void* d_ws, size_t ws_size,
                              hipStream_t stream) {
  const float* x    = (const float*)d_in[0];
  const float* bias = (const float*)d_in[1];
  const int*   seed = (const int*)d_in[2];
  float* out = (float*)d_out;

  const int K = 4096;                       // IN_FEATURES
  const int N = in_sizes[1];                // OUT_FEATURES (4096)
  const int M = in_sizes[0] / K;            // BATCH*SEQ (8192)

  // workspace layout: W bf16 [N*K] then Xb bf16 [M*K]  (33.5MB + 67MB)
  unsigned short* W  = (unsigned short*)d_ws;
  unsigned short* Xb = W + (size_t)N * K;

  genw_kernel<<<8192, 256, 0, stream>>>(W, seed, N * K);
  castx_kernel<<<2048, 256, 0, stream>>>(x, Xb, M * K);

  dim3 grid((M / BM) * (N / BN));
  gemm_bt_bias<<<grid, 256, 0, stream>>>((const __hip_bfloat16*)Xb,
                                         (const __hip_bfloat16*)W,
                                         bias, out, M, N, K);
}

// Round 2
// 359.616 us; speedup vs baseline: 1.2570x; 1.2570x over previous
//
#include <hip/hip_runtime.h>
#include <hip/hip_bf16.h>
#include <cstdint>
#include <math.h>

// ---------------------------------------------------------------------------
// GMemLinear: out = (x @ W^T) + bias, W = jax.random.normal(key(seed),[N,K],f64)
// R2: GEMM ported to the 256^2 8-phase template (T2 swizzle + T3/T4 counted
// vmcnt + T5 setprio). genw/castx unchanged (verified in R1).
// ---------------------------------------------------------------------------

typedef __bf16  bf16x8 __attribute__((ext_vector_type(8)));
typedef float   f32x4  __attribute__((ext_vector_type(4)));
typedef unsigned short u16x8 __attribute__((ext_vector_type(8)));

__device__ __forceinline__ unsigned short f2bf_rne(float f) {
  uint32_t x = __float_as_uint(f);
  uint32_t r = (x + 0x7FFFu + ((x >> 16) & 1u)) >> 16;
  return (unsigned short)r;
}

// Threefry-2x32, 20 rounds (Random123 / JAX).
__device__ __forceinline__ void threefry2x32(uint32_t k0, uint32_t k1,
                                             uint32_t x0, uint32_t x1,
                                             uint32_t& o0, uint32_t& o1) {
  uint32_t ks0 = k0, ks1 = k1, ks2 = k0 ^ k1 ^ 0x1BD11BDAu;
  uint32_t ks[3] = {ks0, ks1, ks2};
  x0 += ks0; x1 += ks1;
  const uint32_t rot0[4] = {13u, 15u, 26u, 6u};
  const uint32_t rot1[4] = {17u, 29u, 16u, 24u};
#pragma unroll
  for (int i = 0; i < 5; ++i) {
    const uint32_t* r = (i & 1) ? rot1 : rot0;
#pragma unroll
    for (int j = 0; j < 4; ++j) {
      x0 += x1;
      x1 = (x1 << r[j]) | (x1 >> (32u - r[j]));
      x1 ^= x0;
    }
    x0 += ks[(i + 1) % 3];
    x1 += ks[(i + 2) % 3] + (uint32_t)(i + 1);
  }
  o0 = x0; o1 = x1;
}

__device__ __forceinline__ double erfinv_mixed(double u) {
  double au = fabs(u);
  double t  = (1.0 - au) * (1.0 + au);
  float  wf = -logf((float)t);
  if (wf < 15.5f) {
    float w, p;
    if (wf < 5.0f) {
      w = wf - 2.5f;
      p = 2.81022636e-08f;
      p = 3.43273939e-07f + p * w;
      p = -3.5233877e-06f + p * w;
      p = -4.39150654e-06f + p * w;
      p = 0.00021858087f + p * w;
      p = -0.00125372503f + p * w;
      p = -0.00417768164f + p * w;
      p = 0.246640727f + p * w;
      p = 1.50140941f + p * w;
    } else {
      w = sqrtf(wf) - 3.0f;
      p = -0.000200214257f;
      p = 0.000100950558f + p * w;
      p = 0.00134934322f + p * w;
      p = -0.00367342844f + p * w;
      p = 0.00573950773f + p * w;
      p = -0.0076224613f + p * w;
      p = 0.00943887047f + p * w;
      p = 1.00167406f + p * w;
      p = 2.83297682f + p * w;
    }
    return (double)(p * (float)u);
  } else {
    double L = -log(1.0 - au);
    double r = sqrt(L);
    r = sqrt(L - log(r) - 0.5723649429247001);
    r = sqrt(L - log(r) - 0.5723649429247001);
    return (u < 0.0) ? -r : r;
  }
}

__global__ void genw_kernel(unsigned short* __restrict__ W,
                            const int* __restrict__ seedp, int total) {
  const uint32_t k1 = (uint32_t)seedp[0];
  const uint32_t k0 = 0u;
  const double DLO = -0x1.fffffffffffffp-1;
  const int nq = total >> 2;
  const int stride = (int)(gridDim.x * blockDim.x);
  for (int q = (int)(blockIdx.x * blockDim.x + threadIdx.x); q < nq; q += stride) {
    ushort4 outv;
    unsigned short tmp[4];
#pragma unroll
    for (int j = 0; j < 4; ++j) {
      uint32_t e = ((uint32_t)q << 2) + (uint32_t)j;
      uint32_t o0, o1;
      threefry2x32(k0, k1, 0u, e, o0, o1);
      uint64_t bits = ((uint64_t)o0 << 32) | (uint64_t)o1;
      uint64_t fb = (bits >> 12) | 0x3FF0000000000000ull;
      union { uint64_t u; double d; } cv; cv.u = fb;
      double f = cv.d - 1.0;
      double u = f * 2.0 + DLO;
      u = fmax(u, DLO);
      double x = erfinv_mixed(u);
      float wv = (float)(1.4142135623730951 * x);
      tmp[j] = f2bf_rne(wv);
    }
    outv.x = tmp[0]; outv.y = tmp[1]; outv.z = tmp[2]; outv.w = tmp[3];
    *(ushort4*)(W + ((size_t)q << 2)) = outv;
  }
}

__global__ void castx_kernel(const float* __restrict__ X,
                             unsigned short* __restrict__ Y, int n) {
  const int n8 = n >> 3;
  const int stride = (int)(gridDim.x * blockDim.x);
  for (int q = (int)(blockIdx.x * blockDim.x + threadIdx.x); q < n8; q += stride) {
    const float4* p = (const float4*)(X + ((size_t)q << 3));
    float4 a = p[0], b = p[1];
    u16x8 o;
    o[0] = f2bf_rne(a.x); o[1] = f2bf_rne(a.y);
    o[2] = f2bf_rne(a.z); o[3] = f2bf_rne(a.w);
    o[4] = f2bf_rne(b.x); o[5] = f2bf_rne(b.y);
    o[6] = f2bf_rne(b.z); o[7] = f2bf_rne(b.w);
    *(u16x8*)(Y + ((size_t)q << 3)) = o;
  }
}

// ---------------------------------------------------------------------------
// 256x256 8-phase bf16 GEMM, C = A[M][K] * B[N][K]^T + bias.
// 8 waves (2Mx4N), BK=64, 128KiB LDS dbuf, counted vmcnt(8), setprio MFMA.
// LDS layout: per K-tile per matrix 32 subtiles of 16rows x 32cols (1KiB),
// swizzle within subtile: byte ^= ((row>>1)&3)<<4 (involution; 2-way banks).
// gload_lds writes one subtile linearly per wave-instr; source pre-swizzled.
// ---------------------------------------------------------------------------

__device__ __forceinline__ void gload_lds16(const void* g, void* l) {
  __builtin_amdgcn_global_load_lds(
      (const __attribute__((address_space(1))) unsigned int*)g,
      (__attribute__((address_space(3))) unsigned int*)l, 16, 0, 0);
}

__global__ __launch_bounds__(512, 2) void gemm256(
    const unsigned short* __restrict__ A,   // [M][K] bf16
    const unsigned short* __restrict__ B,   // [N][K] bf16
    const float* __restrict__ bias,         // [N]
    float* __restrict__ C,                  // [M][N] f32
    int M, int N, int K) {
  __shared__ __align__(1024) char lds[131072];

  const int nwg = (int)gridDim.x;
  int wg = (int)blockIdx.x;
  wg = (wg & 7) * (nwg >> 3) + (wg >> 3);       // bijective: nwg % 8 == 0
  const int ntn = N >> 8;
  const int tm = wg / ntn, tn = wg - tm * ntn;

  const int tid = (int)threadIdx.x;
  const int w = tid >> 6, l = tid & 63;
  const int wr = w >> 2, wc = w & 3;            // wave grid 2(M) x 4(N)
  const int l15 = l & 15;

  // read-side swizzled lane offset within a 1KiB subtile
  int laneRd = (l15 << 6) | ((l >> 4) << 4);
  laneRd ^= ((l15 >> 1) & 3) << 4;
  // stage-side: lane l sources global row (l>>2), col-bytes pre-inverse-swizzled
  const int stRow = l >> 2;
  const int stCol = (((l & 3) ^ ((l >> 3) & 3)) << 4);

  const char* Ag = (const char*)A;
  const char* Bg = (const char*)B;
  const long rowA0 = (long)tm * 256;
  const long rowB0 = (long)tn * 256;
  const long Kb = (long)K;

#define STAGE(ktile_)                                                         \
  {                                                                           \
    const int c_ = (ktile_) & 1;                                              \
    const long kb_ = (long)(ktile_) * 64;                                     \
    char* Ab_ = &lds[c_ * 32768];                                             \
    char* Bb_ = &lds[65536 + c_ * 32768];                                     \
    _Pragma("unroll")                                                         \
    for (int i_ = 0; i_ < 4; ++i_) {                                          \
      const int u_ = w * 4 + i_;                                              \
      const int r4_ = u_ >> 1, s_ = u_ & 1;                                   \
      gload_lds16(Ag + 2 * ((rowA0 + r4_ * 16 + stRow) * Kb + kb_ + s_ * 32) + stCol, \
                  Ab_ + u_ * 1024);                                           \
      gload_lds16(Bg + 2 * ((rowB0 + r4_ * 16 + stRow) * Kb + kb_ + s_ * 32) + stCol, \
                  Bb_ + u_ * 1024);                                           \
    }                                                                         \
  }

#define PHASE(mi0_)                                                           \
  {                                                                           \
    _Pragma("unroll")                                                         \
    for (int dm = 0; dm < 2; ++dm)                                            \
      _Pragma("unroll")                                                       \
      for (int s = 0; s < 2; ++s)                                             \
        aq[dm][s] = *(const bf16x8*)(Abuf + ((wr * 8 + (mi0_) + dm) * 2048 + s * 1024 + laneRd)); \
    __builtin_amdgcn_s_barrier();                                             \
    asm volatile("s_waitcnt lgkmcnt(0)" ::: "memory");                        \
    __builtin_amdgcn_sched_barrier(0);                                        \
    __builtin_amdgcn_s_setprio(1);                                            \
    _Pragma("unroll")                                                         \
    for (int s = 0; s < 2; ++s)                                               \
      _Pragma("unroll")                                                       \
      for (int dm = 0; dm < 2; ++dm)                                          \
        _Pragma("unroll")                                                     \
        for (int ni = 0; ni < 4; ++ni)                                        \
          acc[(mi0_) + dm][ni] = __builtin_amdgcn_mfma_f32_16x16x32_bf16(     \
              aq[dm][s], bq[ni][s], acc[(mi0_) + dm][ni], 0, 0, 0);           \
    __builtin_amdgcn_s_setprio(0);                                            \
    __builtin_amdgcn_s_barrier();                                             \
  }

  f32x4 acc[8][4];
#pragma unroll
  for (int i = 0; i < 8; ++i)
#pragma unroll
    for (int j = 0; j < 4; ++j) acc[i][j] = (f32x4){0.f, 0.f, 0.f, 0.f};

  STAGE(0);
  STAGE(1);

  const int NTt = K >> 6;
  for (int t = 0; t < NTt; ++t) {
    const int c = t & 1;
    const char* Abuf = &lds[c * 32768];
    const char* Bbuf = &lds[65536 + c * 32768];

    // tile entry: retire this tile's 8 loads (next tile's 8 stay in flight)
    if (t + 1 < NTt) { asm volatile("s_waitcnt vmcnt(8)" ::: "memory"); }
    else             { asm volatile("s_waitcnt vmcnt(0)" ::: "memory"); }
    __builtin_amdgcn_sched_barrier(0);
    __builtin_amdgcn_s_barrier();

    // P0: hoist all B fragments for this tile + A fragments mi=0,1
    bf16x8 bq[4][2], aq[2][2];
#pragma unroll
    for (int ni = 0; ni < 4; ++ni)
#pragma unroll
      for (int s = 0; s < 2; ++s)
        bq[ni][s] = *(const bf16x8*)(Bbuf + ((wc * 4 + ni) * 2048 + s * 1024 + laneRd));
    PHASE(0)
    PHASE(2)   // P1
    PHASE(4)   // P2

    // P3 (mi=6,7): drain reads of this buffer, then prefetch tile t+2 into it
#pragma unroll
    for (int dm = 0; dm < 2; ++dm)
#pragma unroll
      for (int s = 0; s < 2; ++s)
        aq[dm][s] = *(const bf16x8*)(Abuf + ((wr * 8 + 6 + dm) * 2048 + s * 1024 + laneRd));
    asm volatile("s_waitcnt lgkmcnt(0)" ::: "memory");
    __builtin_amdgcn_sched_barrier(0);
    __builtin_amdgcn_s_barrier();   // all waves' reads of buf c complete
    if (t + 2 < NTt) STAGE(t + 2);
    __builtin_amdgcn_sched_barrier(0);
    __builtin_amdgcn_s_setprio(1);
#pragma unroll
    for (int s = 0; s < 2; ++s)
#pragma unroll
      for (int dm = 0; dm < 2; ++dm)
#pragma unroll
        for (int ni = 0; ni < 4; ++ni)
          acc[6 + dm][ni] = __builtin_amdgcn_mfma_f32_16x16x32_bf16(
              aq[dm][s], bq[ni][s], acc[6 + dm][ni], 0, 0, 0);
    __builtin_amdgcn_s_setprio(0);
    // trailing barrier provided by next tile's entry barrier
  }

  // epilogue: C/D layout col = lane&15, row = (lane>>4)*4 + j
#pragma unroll
  for (int ni = 0; ni < 4; ++ni) {
    const int col = tn * 256 + wc * 64 + ni * 16 + l15;
    const float bv = bias[col];
#pragma unroll
    for (int mi = 0; mi < 8; ++mi) {
      const int r0 = tm * 256 + wr * 128 + mi * 16 + ((l >> 4) << 2);
      f32x4 v = acc[mi][ni];
#pragma unroll
      for (int j = 0; j < 4; ++j)
        C[(size_t)(r0 + j) * N + col] = v[j] + bv;
    }
  }
#undef STAGE
#undef PHASE
}

// ---------------------------------------------------------------------------
extern "C" void kernel_launch(void* const* d_in, const int* in_sizes, int n_in,
                              void* d_out, int out_size, void* d_ws, size_t ws_size,
                              hipStream_t stream) {
  const float* x    = (const float*)d_in[0];
  const float* bias = (const float*)d_in[1];
  const int*   seed = (const int*)d_in[2];
  float* out = (float*)d_out;

  const int K = 4096;                       // IN_FEATURES
  const int N = in_sizes[1];                // OUT_FEATURES (4096)
  const int M = in_sizes[0] / K;            // BATCH*SEQ (8192)

  unsigned short* W  = (unsigned short*)d_ws;
  unsigned short* Xb = W + (size_t)N * K;

  genw_kernel<<<8192, 256, 0, stream>>>(W, seed, N * K);
  castx_kernel<<<2048, 256, 0, stream>>>(x, Xb, M * K);

  dim3 grid((M / 256) * (N / 256));
  gemm256<<<grid, 512, 0, stream>>>((const unsigned short*)Xb,
                                    (const unsigned short*)W,
                                    bias, out, M, N, K);
}

// Round 3
// 355.522 us; speedup vs baseline: 1.2715x; 1.0115x over previous
//
#include <hip/hip_runtime.h>
#include <hip/hip_bf16.h>
#include <cstdint>
#include <math.h>

// ---------------------------------------------------------------------------
// GMemLinear: out = (x @ W^T) + bias, W = jax.random.normal(key(seed),[N,K],f64)
// R3: same 256^2 8-phase schedule as R2, but ALL LDS fragment reads are
// inline-asm ds_read_b128 (invisible to compiler dep-tracking) so the
// compiler cannot insert vmcnt(0) drains against outstanding global_load_lds.
// K-loop unrolled x2 for compile-time buffer parity.
// ---------------------------------------------------------------------------

typedef __bf16  bf16x8 __attribute__((ext_vector_type(8)));
typedef float   f32x4  __attribute__((ext_vector_type(4)));
typedef unsigned short u16x8 __attribute__((ext_vector_type(8)));

__device__ __forceinline__ unsigned short f2bf_rne(float f) {
  uint32_t x = __float_as_uint(f);
  uint32_t r = (x + 0x7FFFu + ((x >> 16) & 1u)) >> 16;
  return (unsigned short)r;
}

// Threefry-2x32, 20 rounds (Random123 / JAX).
__device__ __forceinline__ void threefry2x32(uint32_t k0, uint32_t k1,
                                             uint32_t x0, uint32_t x1,
                                             uint32_t& o0, uint32_t& o1) {
  uint32_t ks0 = k0, ks1 = k1, ks2 = k0 ^ k1 ^ 0x1BD11BDAu;
  uint32_t ks[3] = {ks0, ks1, ks2};
  x0 += ks0; x1 += ks1;
  const uint32_t rot0[4] = {13u, 15u, 26u, 6u};
  const uint32_t rot1[4] = {17u, 29u, 16u, 24u};
#pragma unroll
  for (int i = 0; i < 5; ++i) {
    const uint32_t* r = (i & 1) ? rot1 : rot0;
#pragma unroll
    for (int j = 0; j < 4; ++j) {
      x0 += x1;
      x1 = (x1 << r[j]) | (x1 >> (32u - r[j]));
      x1 ^= x0;
    }
    x0 += ks[(i + 1) % 3];
    x1 += ks[(i + 2) % 3] + (uint32_t)(i + 1);
  }
  o0 = x0; o1 = x1;
}

__device__ __forceinline__ double erfinv_mixed(double u) {
  double au = fabs(u);
  double t  = (1.0 - au) * (1.0 + au);
  float  wf = -logf((float)t);
  if (wf < 15.5f) {
    float w, p;
    if (wf < 5.0f) {
      w = wf - 2.5f;
      p = 2.81022636e-08f;
      p = 3.43273939e-07f + p * w;
      p = -3.5233877e-06f + p * w;
      p = -4.39150654e-06f + p * w;
      p = 0.00021858087f + p * w;
      p = -0.00125372503f + p * w;
      p = -0.00417768164f + p * w;
      p = 0.246640727f + p * w;
      p = 1.50140941f + p * w;
    } else {
      w = sqrtf(wf) - 3.0f;
      p = -0.000200214257f;
      p = 0.000100950558f + p * w;
      p = 0.00134934322f + p * w;
      p = -0.00367342844f + p * w;
      p = 0.00573950773f + p * w;
      p = -0.0076224613f + p * w;
      p = 0.00943887047f + p * w;
      p = 1.00167406f + p * w;
      p = 2.83297682f + p * w;
    }
    return (double)(p * (float)u);
  } else {
    double L = -log(1.0 - au);
    double r = sqrt(L);
    r = sqrt(L - log(r) - 0.5723649429247001);
    r = sqrt(L - log(r) - 0.5723649429247001);
    return (u < 0.0) ? -r : r;
  }
}

__global__ void genw_kernel(unsigned short* __restrict__ W,
                            const int* __restrict__ seedp, int total) {
  const uint32_t k1 = (uint32_t)seedp[0];
  const uint32_t k0 = 0u;
  const double DLO = -0x1.fffffffffffffp-1;
  const int nq = total >> 2;
  const int stride = (int)(gridDim.x * blockDim.x);
  for (int q = (int)(blockIdx.x * blockDim.x + threadIdx.x); q < nq; q += stride) {
    ushort4 outv;
    unsigned short tmp[4];
#pragma unroll
    for (int j = 0; j < 4; ++j) {
      uint32_t e = ((uint32_t)q << 2) + (uint32_t)j;
      uint32_t o0, o1;
      threefry2x32(k0, k1, 0u, e, o0, o1);
      uint64_t bits = ((uint64_t)o0 << 32) | (uint64_t)o1;
      uint64_t fb = (bits >> 12) | 0x3FF0000000000000ull;
      union { uint64_t u; double d; } cv; cv.u = fb;
      double f = cv.d - 1.0;
      double u = f * 2.0 + DLO;
      u = fmax(u, DLO);
      double x = erfinv_mixed(u);
      float wv = (float)(1.4142135623730951 * x);
      tmp[j] = f2bf_rne(wv);
    }
    outv.x = tmp[0]; outv.y = tmp[1]; outv.z = tmp[2]; outv.w = tmp[3];
    *(ushort4*)(W + ((size_t)q << 2)) = outv;
  }
}

__global__ void castx_kernel(const float* __restrict__ X,
                             unsigned short* __restrict__ Y, int n) {
  const int n8 = n >> 3;
  const int stride = (int)(gridDim.x * blockDim.x);
  for (int q = (int)(blockIdx.x * blockDim.x + threadIdx.x); q < n8; q += stride) {
    const float4* p = (const float4*)(X + ((size_t)q << 3));
    float4 a = p[0], b = p[1];
    u16x8 o;
    o[0] = f2bf_rne(a.x); o[1] = f2bf_rne(a.y);
    o[2] = f2bf_rne(a.z); o[3] = f2bf_rne(a.w);
    o[4] = f2bf_rne(b.x); o[5] = f2bf_rne(b.y);
    o[6] = f2bf_rne(b.z); o[7] = f2bf_rne(b.w);
    *(u16x8*)(Y + ((size_t)q << 3)) = o;
  }
}

// ---------------------------------------------------------------------------
// 256x256 8-phase bf16 GEMM with asm ds_read (no compiler waitcnt insertion).
// ---------------------------------------------------------------------------

__device__ __forceinline__ void gload_lds16(const void* g, void* l) {
  __builtin_amdgcn_global_load_lds(
      (const __attribute__((address_space(1))) unsigned int*)g,
      (__attribute__((address_space(3))) unsigned int*)l, 16, 0, 0);
}

__device__ __forceinline__ uint32_t lds_u32(void* p) {
  return (uint32_t)(uintptr_t)(__attribute__((address_space(3))) char*)p;
}

template <int OFF>
__device__ __forceinline__ bf16x8 dsr16(uint32_t a) {
  bf16x8 r;
  asm volatile("ds_read_b128 %0, %1 offset:%2" : "=v"(r) : "v"(a), "i"(OFF));
  return r;
}

__global__ __launch_bounds__(512, 2) void gemm256(
    const unsigned short* __restrict__ A,   // [M][K] bf16
    const unsigned short* __restrict__ B,   // [N][K] bf16
    const float* __restrict__ bias,         // [N]
    float* __restrict__ C,                  // [M][N] f32
    int M, int N, int K) {
  __shared__ __align__(1024) char lds[131072];

  const int nwg = (int)gridDim.x;
  int wg = (int)blockIdx.x;
  wg = (wg & 7) * (nwg >> 3) + (wg >> 3);       // bijective: nwg % 8 == 0
  const int ntn = N >> 8;
  const int tm = wg / ntn, tn = wg - tm * ntn;

  const int tid = (int)threadIdx.x;
  const int w = tid >> 6, l = tid & 63;
  const int wr = w >> 2, wc = w & 3;            // wave grid 2(M) x 4(N)
  const int l15 = l & 15;

  // read-side swizzled lane offset within a 1KiB (16row x 32col) subtile
  int laneRd = (l15 << 6) | ((l >> 4) << 4);
  laneRd ^= ((l15 >> 1) & 3) << 4;
  // stage-side: lane l sources global row l>>2, col-slot pre-inverse-swizzled
  const int stRow = l >> 2;
  const int stCol = (((l & 3) ^ ((l >> 3) & 3)) << 4);

  const char* Ag = (const char*)A;
  const char* Bg = (const char*)B;
  const long rowA0 = (long)tm * 256;
  const long rowB0 = (long)tn * 256;
  const long Kb = (long)K;

  const uint32_t lds0  = lds_u32(&lds[0]);
  const uint32_t aBase = lds0 + (uint32_t)(wr * 16384 + laneRd);
  const uint32_t bBase = lds0 + 65536u + (uint32_t)(wc * 8192 + laneRd);

#define STAGE(kt_, c_)                                                        \
  {                                                                           \
    const long kb_ = (long)(kt_) * 64;                                        \
    char* Ab_ = &lds[(c_) * 32768];                                           \
    char* Bb_ = &lds[65536 + (c_) * 32768];                                   \
    _Pragma("unroll")                                                         \
    for (int i_ = 0; i_ < 4; ++i_) {                                          \
      const int u_ = w * 4 + i_;                                              \
      const int r4_ = u_ >> 1, s_ = u_ & 1;                                   \
      gload_lds16(Ag + 2 * ((rowA0 + r4_ * 16 + stRow) * Kb + kb_ + s_ * 32) + stCol, \
                  Ab_ + u_ * 1024);                                           \
      gload_lds16(Bg + 2 * ((rowB0 + r4_ * 16 + stRow) * Kb + kb_ + s_ * 32) + stCol, \
                  Bb_ + u_ * 1024);                                           \
    }                                                                         \
  }

#define BRD(base_)                                                            \
  bq[0][0] = dsr16<0>(base_);    bq[0][1] = dsr16<1024>(base_);               \
  bq[1][0] = dsr16<2048>(base_); bq[1][1] = dsr16<3072>(base_);               \
  bq[2][0] = dsr16<4096>(base_); bq[2][1] = dsr16<5120>(base_);               \
  bq[3][0] = dsr16<6144>(base_); bq[3][1] = dsr16<7168>(base_);

#define ARD(mi0_, base_)                                                      \
  aq[0][0] = dsr16<(mi0_) * 2048>(base_);                                     \
  aq[0][1] = dsr16<(mi0_) * 2048 + 1024>(base_);                              \
  aq[1][0] = dsr16<((mi0_) + 1) * 2048>(base_);                               \
  aq[1][1] = dsr16<((mi0_) + 1) * 2048 + 1024>(base_);

#define MFMA16(mi0_)                                                          \
  _Pragma("unroll")                                                           \
  for (int s = 0; s < 2; ++s)                                                 \
    _Pragma("unroll")                                                         \
    for (int dm = 0; dm < 2; ++dm)                                            \
      _Pragma("unroll")                                                       \
      for (int ni = 0; ni < 4; ++ni)                                          \
        acc[(mi0_) + dm][ni] = __builtin_amdgcn_mfma_f32_16x16x32_bf16(       \
            aq[dm][s], bq[ni][s], acc[(mi0_) + dm][ni], 0, 0, 0);

#define LGKM0_FENCE                                                           \
  asm volatile("s_waitcnt lgkmcnt(0)" ::: "memory");                          \
  __builtin_amdgcn_sched_barrier(0);

#define TILE_BODY(t_, c_)                                                     \
  {                                                                           \
    const uint32_t aB = aBase + (c_) * 32768u;                                \
    const uint32_t bB = bBase + (c_) * 32768u;                                \
    if ((t_) + 1 < NTt) { asm volatile("s_waitcnt vmcnt(8)" ::: "memory"); }  \
    else                { asm volatile("s_waitcnt vmcnt(0)" ::: "memory"); }  \
    __builtin_amdgcn_sched_barrier(0);                                        \
    __builtin_amdgcn_s_barrier();                                             \
    bf16x8 aq[2][2], bq[4][2];                                                \
    BRD(bB)                                                                   \
    ARD(0, aB)                                                                \
    __builtin_amdgcn_s_barrier();                                             \
    LGKM0_FENCE                                                               \
    __builtin_amdgcn_s_setprio(1);                                            \
    MFMA16(0)                                                                 \
    __builtin_amdgcn_s_setprio(0);                                            \
    __builtin_amdgcn_s_barrier();                                             \
    ARD(2, aB)                                                                \
    __builtin_amdgcn_s_barrier();                                             \
    LGKM0_FENCE                                                               \
    __builtin_amdgcn_s_setprio(1);                                            \
    MFMA16(2)                                                                 \
    __builtin_amdgcn_s_setprio(0);                                            \
    __builtin_amdgcn_s_barrier();                                             \
    ARD(4, aB)                                                                \
    __builtin_amdgcn_s_barrier();                                             \
    LGKM0_FENCE                                                               \
    __builtin_amdgcn_s_setprio(1);                                            \
    MFMA16(4)                                                                 \
    __builtin_amdgcn_s_setprio(0);                                            \
    __builtin_amdgcn_s_barrier();                                             \
    ARD(6, aB)                                                                \
    LGKM0_FENCE                                                               \
    __builtin_amdgcn_s_barrier();                                             \
    if ((t_) + 2 < NTt) STAGE((t_) + 2, c_)                                   \
    __builtin_amdgcn_sched_barrier(0);                                        \
    __builtin_amdgcn_s_setprio(1);                                            \
    MFMA16(6)                                                                 \
    __builtin_amdgcn_s_setprio(0);                                            \
  }

  f32x4 acc[8][4];
#pragma unroll
  for (int i = 0; i < 8; ++i)
#pragma unroll
    for (int j = 0; j < 4; ++j) acc[i][j] = (f32x4){0.f, 0.f, 0.f, 0.f};

  const int NTt = K >> 6;   // 64
  STAGE(0, 0)
  STAGE(1, 1)

  for (int t = 0; t < NTt; t += 2) {
    TILE_BODY(t, 0)
    TILE_BODY(t + 1, 1)
  }

  // epilogue: C/D layout col = lane&15, row = (lane>>4)*4 + j
#pragma unroll
  for (int ni = 0; ni < 4; ++ni) {
    const int col = tn * 256 + wc * 64 + ni * 16 + l15;
    const float bv = bias[col];
#pragma unroll
    for (int mi = 0; mi < 8; ++mi) {
      const int r0 = tm * 256 + wr * 128 + mi * 16 + ((l >> 4) << 2);
      f32x4 v = acc[mi][ni];
#pragma unroll
      for (int j = 0; j < 4; ++j)
        C[(size_t)(r0 + j) * N + col] = v[j] + bv;
    }
  }
#undef STAGE
#undef BRD
#undef ARD
#undef MFMA16
#undef LGKM0_FENCE
#undef TILE_BODY
}

// ---------------------------------------------------------------------------
extern "C" void kernel_launch(void* const* d_in, const int* in_sizes, int n_in,
                              void* d_out, int out_size, void* d_ws, size_t ws_size,
                              hipStream_t stream) {
  const float* x    = (const float*)d_in[0];
  const float* bias = (const float*)d_in[1];
  const int*   seed = (const int*)d_in[2];
  float* out = (float*)d_out;

  const int K = 4096;                       // IN_FEATURES
  const int N = in_sizes[1];                // OUT_FEATURES (4096)
  const int M = in_sizes[0] / K;            // BATCH*SEQ (8192)

  unsigned short* W  = (unsigned short*)d_ws;
  unsigned short* Xb = W + (size_t)N * K;

  genw_kernel<<<8192, 256, 0, stream>>>(W, seed, N * K);
  castx_kernel<<<2048, 256, 0, stream>>>(x, Xb, M * K);

  dim3 grid((M / 256) * (N / 256));
  gemm256<<<grid, 512, 0, stream>>>((const unsigned short*)Xb,
                                    (const unsigned short*)W,
                                    bias, out, M, N, K);
}

// Round 5
// 330.121 us; speedup vs baseline: 1.3694x; 1.0769x over previous
//
#include <hip/hip_runtime.h>
#include <hip/hip_bf16.h>
#include <cstdint>
#include <math.h>

// ---------------------------------------------------------------------------
// GMemLinear: out = (x @ W^T) + bias, W = jax.random.normal(key(seed),[N,K],f64)
// R5 = R4 resubmit (container died on infra error, no measurement).
// GEMM: quad-buffered BK=32 pipeline, 4 LDS buffers x 32KB, 3-tile-deep
// prefetch, 2 gload_lds spread per phase (no drain barrier), per-phase
// {reads; stage; barrier; lgkm0; setprio; 16 MFMA; setprio; barrier},
// counted vmcnt(8) once per tile. Swizzle/numerics identical to R2/R3.
// ---------------------------------------------------------------------------

typedef __bf16  bf16x8 __attribute__((ext_vector_type(8)));
typedef float   f32x4  __attribute__((ext_vector_type(4)));
typedef unsigned short u16x8 __attribute__((ext_vector_type(8)));

__device__ __forceinline__ unsigned short f2bf_rne(float f) {
  uint32_t x = __float_as_uint(f);
  uint32_t r = (x + 0x7FFFu + ((x >> 16) & 1u)) >> 16;
  return (unsigned short)r;
}

// Threefry-2x32, 20 rounds (Random123 / JAX).
__device__ __forceinline__ void threefry2x32(uint32_t k0, uint32_t k1,
                                             uint32_t x0, uint32_t x1,
                                             uint32_t& o0, uint32_t& o1) {
  uint32_t ks0 = k0, ks1 = k1, ks2 = k0 ^ k1 ^ 0x1BD11BDAu;
  uint32_t ks[3] = {ks0, ks1, ks2};
  x0 += ks0; x1 += ks1;
  const uint32_t rot0[4] = {13u, 15u, 26u, 6u};
  const uint32_t rot1[4] = {17u, 29u, 16u, 24u};
#pragma unroll
  for (int i = 0; i < 5; ++i) {
    const uint32_t* r = (i & 1) ? rot1 : rot0;
#pragma unroll
    for (int j = 0; j < 4; ++j) {
      x0 += x1;
      x1 = (x1 << r[j]) | (x1 >> (32u - r[j]));
      x1 ^= x0;
    }
    x0 += ks[(i + 1) % 3];
    x1 += ks[(i + 2) % 3] + (uint32_t)(i + 1);
  }
  o0 = x0; o1 = x1;
}

__device__ __forceinline__ double erfinv_mixed(double u) {
  double au = fabs(u);
  double t  = (1.0 - au) * (1.0 + au);
  float  wf = -logf((float)t);
  if (wf < 15.5f) {
    float w, p;
    if (wf < 5.0f) {
      w = wf - 2.5f;
      p = 2.81022636e-08f;
      p = 3.43273939e-07f + p * w;
      p = -3.5233877e-06f + p * w;
      p = -4.39150654e-06f + p * w;
      p = 0.00021858087f + p * w;
      p = -0.00125372503f + p * w;
      p = -0.00417768164f + p * w;
      p = 0.246640727f + p * w;
      p = 1.50140941f + p * w;
    } else {
      w = sqrtf(wf) - 3.0f;
      p = -0.000200214257f;
      p = 0.000100950558f + p * w;
      p = 0.00134934322f + p * w;
      p = -0.00367342844f + p * w;
      p = 0.00573950773f + p * w;
      p = -0.0076224613f + p * w;
      p = 0.00943887047f + p * w;
      p = 1.00167406f + p * w;
      p = 2.83297682f + p * w;
    }
    return (double)(p * (float)u);
  } else {
    double L = -log(1.0 - au);
    double r = sqrt(L);
    r = sqrt(L - log(r) - 0.5723649429247001);
    r = sqrt(L - log(r) - 0.5723649429247001);
    return (u < 0.0) ? -r : r;
  }
}

__global__ void genw_kernel(unsigned short* __restrict__ W,
                            const int* __restrict__ seedp, int total) {
  const uint32_t k1 = (uint32_t)seedp[0];
  const uint32_t k0 = 0u;
  const double DLO = -0x1.fffffffffffffp-1;
  const int nq = total >> 2;
  const int stride = (int)(gridDim.x * blockDim.x);
  for (int q = (int)(blockIdx.x * blockDim.x + threadIdx.x); q < nq; q += stride) {
    ushort4 outv;
    unsigned short tmp[4];
#pragma unroll
    for (int j = 0; j < 4; ++j) {
      uint32_t e = ((uint32_t)q << 2) + (uint32_t)j;
      uint32_t o0, o1;
      threefry2x32(k0, k1, 0u, e, o0, o1);
      uint64_t bits = ((uint64_t)o0 << 32) | (uint64_t)o1;
      uint64_t fb = (bits >> 12) | 0x3FF0000000000000ull;
      union { uint64_t u; double d; } cv; cv.u = fb;
      double f = cv.d - 1.0;
      double u = f * 2.0 + DLO;
      u = fmax(u, DLO);
      double x = erfinv_mixed(u);
      float wv = (float)(1.4142135623730951 * x);
      tmp[j] = f2bf_rne(wv);
    }
    outv.x = tmp[0]; outv.y = tmp[1]; outv.z = tmp[2]; outv.w = tmp[3];
    *(ushort4*)(W + ((size_t)q << 2)) = outv;
  }
}

__global__ void castx_kernel(const float* __restrict__ X,
                             unsigned short* __restrict__ Y, int n) {
  const int n8 = n >> 3;
  const int stride = (int)(gridDim.x * blockDim.x);
  for (int q = (int)(blockIdx.x * blockDim.x + threadIdx.x); q < n8; q += stride) {
    const float4* p = (const float4*)(X + ((size_t)q << 3));
    float4 a = p[0], b = p[1];
    u16x8 o;
    o[0] = f2bf_rne(a.x); o[1] = f2bf_rne(a.y);
    o[2] = f2bf_rne(a.z); o[3] = f2bf_rne(a.w);
    o[4] = f2bf_rne(b.x); o[5] = f2bf_rne(b.y);
    o[6] = f2bf_rne(b.z); o[7] = f2bf_rne(b.w);
    *(u16x8*)(Y + ((size_t)q << 3)) = o;
  }
}

// ---------------------------------------------------------------------------
// 256x256 GEMM, BK=32, quad-buffer, spread staging, counted vmcnt.
// LDS buf c (32KB): A subtiles 0..15 (1KB = 16 rows x 64B), B subtiles at +16K.
// ---------------------------------------------------------------------------

__device__ __forceinline__ void gload_lds16(const void* g, void* l) {
  __builtin_amdgcn_global_load_lds(
      (const __attribute__((address_space(1))) unsigned int*)g,
      (__attribute__((address_space(3))) unsigned int*)l, 16, 0, 0);
}

__device__ __forceinline__ uint32_t lds_u32(void* p) {
  return (uint32_t)(uintptr_t)(__attribute__((address_space(3))) char*)p;
}

template <int OFF>
__device__ __forceinline__ bf16x8 dsr16(uint32_t a) {
  bf16x8 r;
  asm volatile("ds_read_b128 %0, %1 offset:%2" : "=v"(r) : "v"(a), "i"(OFF));
  return r;
}

__global__ __launch_bounds__(512, 2) void gemm256(
    const unsigned short* __restrict__ A,   // [M][K] bf16
    const unsigned short* __restrict__ B,   // [N][K] bf16
    const float* __restrict__ bias,         // [N]
    float* __restrict__ C,                  // [M][N] f32
    int M, int N, int K) {
  __shared__ __align__(1024) char lds[131072];

  const int nwg = (int)gridDim.x;
  int wg = (int)blockIdx.x;
  wg = (wg & 7) * (nwg >> 3) + (wg >> 3);       // bijective: nwg % 8 == 0
  const int ntn = N >> 8;
  const int tm = wg / ntn, tn = wg - tm * ntn;

  const int tid = (int)threadIdx.x;
  const int w = tid >> 6, l = tid & 63;
  const int wr = w >> 2, wc = w & 3;            // wave grid 2(M) x 4(N)
  const int l15 = l & 15;

  // read-side swizzled lane offset within a 1KiB (16row x 64B) subtile
  int laneRd = (l15 << 6) | ((l >> 4) << 4);
  laneRd ^= ((l15 >> 1) & 3) << 4;
  // stage-side: lane l sources global row l>>2, col-slot pre-inverse-swizzled
  const int stRow = l >> 2;
  const int stCol = (((l & 3) ^ ((l >> 3) & 3)) << 4);

  const char* Ag = (const char*)A;
  const char* Bg = (const char*)B;
  const long rowA0 = (long)tm * 256;
  const long rowB0 = (long)tn * 256;
  const long Kb = (long)K;

  const uint32_t lds0  = lds_u32(&lds[0]);
  const uint32_t aBase = lds0 + (uint32_t)(wr * 8192 + laneRd);
  const uint32_t bBase = lds0 + 16384u + (uint32_t)(wc * 4096 + laneRd);

  // stage 2 subtiles (u = w*2, w*2+1) of tile kt_ into buffer cs_
#define STAGE_A(kt_, cs_)                                                     \
  _Pragma("unroll")                                                           \
  for (int i_ = 0; i_ < 2; ++i_) {                                            \
    const int u_ = w * 2 + i_;                                                \
    gload_lds16(Ag + 2 * ((rowA0 + u_ * 16 + stRow) * Kb + (long)(kt_) * 32) + stCol, \
                &lds[(cs_) * 32768 + u_ * 1024]);                             \
  }
#define STAGE_B(kt_, cs_)                                                     \
  _Pragma("unroll")                                                           \
  for (int i_ = 0; i_ < 2; ++i_) {                                            \
    const int u_ = w * 2 + i_;                                                \
    gload_lds16(Bg + 2 * ((rowB0 + u_ * 16 + stRow) * Kb + (long)(kt_) * 32) + stCol, \
                &lds[(cs_) * 32768 + 16384 + u_ * 1024]);                     \
  }

#define MFMA16(base_)                                                         \
  _Pragma("unroll")                                                           \
  for (int mi = 0; mi < 4; ++mi)                                              \
    _Pragma("unroll")                                                         \
    for (int ni = 0; ni < 4; ++ni)                                            \
      acc[(base_) + mi][ni] = __builtin_amdgcn_mfma_f32_16x16x32_bf16(        \
          aq[mi], bq[ni], acc[(base_) + mi][ni], 0, 0, 0);

// One BK=32 tile: c_ = buffer (compile-time 0..3), kt_ = K-tile index,
// vm_ = vmcnt literal at tile end, st_ = stage tile kt_+3 into (c_+3)&3.
#define TILE_BODY(c_, kt_, vm_, st_)                                          \
  {                                                                           \
    const uint32_t aB = aBase + (c_) * 32768u;                                \
    const uint32_t bB = bBase + (c_) * 32768u;                                \
    bf16x8 aq[4], bq[4];                                                      \
    bq[0] = dsr16<0>(bB);    bq[1] = dsr16<1024>(bB);                         \
    bq[2] = dsr16<2048>(bB); bq[3] = dsr16<3072>(bB);                         \
    aq[0] = dsr16<0>(aB);    aq[1] = dsr16<1024>(aB);                         \
    aq[2] = dsr16<2048>(aB); aq[3] = dsr16<3072>(aB);                         \
    if (st_) { STAGE_A((kt_) + 3, ((c_) + 3) & 3) }                           \
    __builtin_amdgcn_s_barrier();                                             \
    asm volatile("s_waitcnt lgkmcnt(0)" ::: "memory");                        \
    __builtin_amdgcn_sched_barrier(0);                                        \
    __builtin_amdgcn_s_setprio(1);                                            \
    MFMA16(0)                                                                 \
    __builtin_amdgcn_s_setprio(0);                                            \
    __builtin_amdgcn_s_barrier();                                             \
    aq[0] = dsr16<4096>(aB); aq[1] = dsr16<5120>(aB);                         \
    aq[2] = dsr16<6144>(aB); aq[3] = dsr16<7168>(aB);                         \
    if (st_) { STAGE_B((kt_) + 3, ((c_) + 3) & 3) }                           \
    __builtin_amdgcn_s_barrier();                                             \
    asm volatile("s_waitcnt lgkmcnt(0)" ::: "memory");                        \
    __builtin_amdgcn_sched_barrier(0);                                        \
    __builtin_amdgcn_s_setprio(1);                                            \
    MFMA16(4)                                                                 \
    __builtin_amdgcn_s_setprio(0);                                            \
    asm volatile("s_waitcnt vmcnt(" #vm_ ")" ::: "memory");                   \
    __builtin_amdgcn_sched_barrier(0);                                        \
    __builtin_amdgcn_s_barrier();                                             \
  }

  f32x4 acc[8][4];
#pragma unroll
  for (int i = 0; i < 8; ++i)
#pragma unroll
    for (int j = 0; j < 4; ++j) acc[i][j] = (f32x4){0.f, 0.f, 0.f, 0.f};

  const int NTt = K >> 5;   // 128 K-tiles of BK=32

  // prologue: stage tiles 0,1,2 into buffers 0,1,2 (12 gloads/wave)
  STAGE_A(0, 0) STAGE_B(0, 0)
  STAGE_A(1, 1) STAGE_B(1, 1)
  STAGE_A(2, 2) STAGE_B(2, 2)
  asm volatile("s_waitcnt vmcnt(8)" ::: "memory");   // tile 0's 4 retired
  __builtin_amdgcn_sched_barrier(0);
  __builtin_amdgcn_s_barrier();

  int kt = 0;
  for (; kt + 7 < NTt; kt += 4) {
    TILE_BODY(0, kt,     8, 1)
    TILE_BODY(1, kt + 1, 8, 1)
    TILE_BODY(2, kt + 2, 8, 1)
    TILE_BODY(3, kt + 3, 8, 1)
  }
  // peel: tiles NTt-4 .. NTt-1 (NTt % 4 == 0)
  TILE_BODY(0, kt,     8, 1)   // stages tile NTt-1
  TILE_BODY(1, kt + 1, 4, 0)
  TILE_BODY(2, kt + 2, 0, 0)
  TILE_BODY(3, kt + 3, 0, 0)

  // epilogue: C/D layout col = lane&15, row = (lane>>4)*4 + j
#pragma unroll
  for (int ni = 0; ni < 4; ++ni) {
    const int col = tn * 256 + wc * 64 + ni * 16 + l15;
    const float bv = bias[col];
#pragma unroll
    for (int mi = 0; mi < 8; ++mi) {
      const int r0 = tm * 256 + wr * 128 + mi * 16 + ((l >> 4) << 2);
      f32x4 v = acc[mi][ni];
#pragma unroll
      for (int j = 0; j < 4; ++j)
        C[(size_t)(r0 + j) * N + col] = v[j] + bv;
    }
  }
#undef STAGE_A
#undef STAGE_B
#undef MFMA16
#undef TILE_BODY
}

// ---------------------------------------------------------------------------
extern "C" void kernel_launch(void* const* d_in, const int* in_sizes, int n_in,
                              void* d_out, int out_size, void* d_ws, size_t ws_size,
                              hipStream_t stream) {
  const float* x    = (const float*)d_in[0];
  const float* bias = (const float*)d_in[1];
  const int*   seed = (const int*)d_in[2];
  float* out = (float*)d_out;

  const int K = 4096;                       // IN_FEATURES
  const int N = in_sizes[1];                // OUT_FEATURES (4096)
  const int M = in_sizes[0] / K;            // BATCH*SEQ (8192)

  unsigned short* W  = (unsigned short*)d_ws;
  unsigned short* Xb = W + (size_t)N * K;

  genw_kernel<<<8192, 256, 0, stream>>>(W, seed, N * K);
  castx_kernel<<<2048, 256, 0, stream>>>(x, Xb, M * K);

  dim3 grid((M / 256) * (N / 256));
  gemm256<<<grid, 512, 0, stream>>>((const unsigned short*)Xb,
                                    (const unsigned short*)W,
                                    bias, out, M, N, K);
}

// Round 6
// 314.869 us; speedup vs baseline: 1.4357x; 1.0484x over previous
//
#include <hip/hip_runtime.h>
#include <hip/hip_bf16.h>
#include <cstdint>
#include <math.h>

// ---------------------------------------------------------------------------
// GMemLinear: out = (x @ W^T) + bias, W = jax.random.normal(key(seed),[N,K],f64)
// R6: (a) GEMM = R5 quad-buffer BK=32 pipeline with alignment-only barriers
// removed (2 barriers/tile: pre-MFMA + end-of-tile); (b) genw+castx fused
// into one kernel (overlap VALU-bound PRNG with HBM-bound cast).
// ---------------------------------------------------------------------------

typedef __bf16  bf16x8 __attribute__((ext_vector_type(8)));
typedef float   f32x4  __attribute__((ext_vector_type(4)));
typedef unsigned short u16x8 __attribute__((ext_vector_type(8)));

__device__ __forceinline__ unsigned short f2bf_rne(float f) {
  uint32_t x = __float_as_uint(f);
  uint32_t r = (x + 0x7FFFu + ((x >> 16) & 1u)) >> 16;
  return (unsigned short)r;
}

// Threefry-2x32, 20 rounds (Random123 / JAX).
__device__ __forceinline__ void threefry2x32(uint32_t k0, uint32_t k1,
                                             uint32_t x0, uint32_t x1,
                                             uint32_t& o0, uint32_t& o1) {
  uint32_t ks0 = k0, ks1 = k1, ks2 = k0 ^ k1 ^ 0x1BD11BDAu;
  uint32_t ks[3] = {ks0, ks1, ks2};
  x0 += ks0; x1 += ks1;
  const uint32_t rot0[4] = {13u, 15u, 26u, 6u};
  const uint32_t rot1[4] = {17u, 29u, 16u, 24u};
#pragma unroll
  for (int i = 0; i < 5; ++i) {
    const uint32_t* r = (i & 1) ? rot1 : rot0;
#pragma unroll
    for (int j = 0; j < 4; ++j) {
      x0 += x1;
      x1 = (x1 << r[j]) | (x1 >> (32u - r[j]));
      x1 ^= x0;
    }
    x0 += ks[(i + 1) % 3];
    x1 += ks[(i + 2) % 3] + (uint32_t)(i + 1);
  }
  o0 = x0; o1 = x1;
}

__device__ __forceinline__ double erfinv_mixed(double u) {
  double au = fabs(u);
  double t  = (1.0 - au) * (1.0 + au);
  float  wf = -logf((float)t);
  if (wf < 15.5f) {
    float w, p;
    if (wf < 5.0f) {
      w = wf - 2.5f;
      p = 2.81022636e-08f;
      p = 3.43273939e-07f + p * w;
      p = -3.5233877e-06f + p * w;
      p = -4.39150654e-06f + p * w;
      p = 0.00021858087f + p * w;
      p = -0.00125372503f + p * w;
      p = -0.00417768164f + p * w;
      p = 0.246640727f + p * w;
      p = 1.50140941f + p * w;
    } else {
      w = sqrtf(wf) - 3.0f;
      p = -0.000200214257f;
      p = 0.000100950558f + p * w;
      p = 0.00134934322f + p * w;
      p = -0.00367342844f + p * w;
      p = 0.00573950773f + p * w;
      p = -0.0076224613f + p * w;
      p = 0.00943887047f + p * w;
      p = 1.00167406f + p * w;
      p = 2.83297682f + p * w;
    }
    return (double)(p * (float)u);
  } else {
    double L = -log(1.0 - au);
    double r = sqrt(L);
    r = sqrt(L - log(r) - 0.5723649429247001);
    r = sqrt(L - log(r) - 0.5723649429247001);
    return (u < 0.0) ? -r : r;
  }
}

// ---------------------------------------------------------------------------
// Fused pre-kernel: blocks [0,2048) cast x f32->bf16; blocks [2048,8192)
// regenerate W (threefry partitionable + erfinv) as bf16.
// ---------------------------------------------------------------------------
__global__ void gen_and_cast(const float* __restrict__ X,
                             unsigned short* __restrict__ Y,
                             unsigned short* __restrict__ W,
                             const int* __restrict__ seedp,
                             int nx, int nw) {
  const int tid = (int)threadIdx.x;
  if (blockIdx.x < 2048) {
    const int n8 = nx >> 3;
    const int stride = 2048 * 256;
    for (int q = (int)(blockIdx.x * 256 + tid); q < n8; q += stride) {
      const float4* p = (const float4*)(X + ((size_t)q << 3));
      float4 a = p[0], b = p[1];
      u16x8 o;
      o[0] = f2bf_rne(a.x); o[1] = f2bf_rne(a.y);
      o[2] = f2bf_rne(a.z); o[3] = f2bf_rne(a.w);
      o[4] = f2bf_rne(b.x); o[5] = f2bf_rne(b.y);
      o[6] = f2bf_rne(b.z); o[7] = f2bf_rne(b.w);
      *(u16x8*)(Y + ((size_t)q << 3)) = o;
    }
  } else {
    const uint32_t k1 = (uint32_t)seedp[0];
    const uint32_t k0 = 0u;
    const double DLO = -0x1.fffffffffffffp-1;   // -(1 - 2^-53)
    const int nq = nw >> 2;
    const int stride = 6144 * 256;
    for (int q = (int)((blockIdx.x - 2048) * 256 + tid); q < nq; q += stride) {
      ushort4 outv;
      unsigned short tmp[4];
#pragma unroll
      for (int j = 0; j < 4; ++j) {
        uint32_t e = ((uint32_t)q << 2) + (uint32_t)j;
        uint32_t o0, o1;
        threefry2x32(k0, k1, 0u, e, o0, o1);
        uint64_t bits = ((uint64_t)o0 << 32) | (uint64_t)o1;
        uint64_t fb = (bits >> 12) | 0x3FF0000000000000ull;
        union { uint64_t u; double d; } cv; cv.u = fb;
        double f = cv.d - 1.0;
        double u = f * 2.0 + DLO;
        u = fmax(u, DLO);
        double x = erfinv_mixed(u);
        float wv = (float)(1.4142135623730951 * x);
        tmp[j] = f2bf_rne(wv);
      }
      outv.x = tmp[0]; outv.y = tmp[1]; outv.z = tmp[2]; outv.w = tmp[3];
      *(ushort4*)(W + ((size_t)q << 2)) = outv;
    }
  }
}

// ---------------------------------------------------------------------------
// 256x256 GEMM, BK=32, quad-buffer, spread staging, counted vmcnt.
// LDS buf c (32KB): A subtiles 0..15 (1KB = 16 rows x 64B), B subtiles at +16K.
// Barriers per tile: 1 pre-MFMA (after all waves issue phase-1 reads+stage)
// + 1 end-of-tile (after counted vmcnt). All other hazards are per-wave
// lgkmcnt(0) fences; staging targets a buffer last read 3 tiles ago.
// ---------------------------------------------------------------------------

__device__ __forceinline__ void gload_lds16(const void* g, void* l) {
  __builtin_amdgcn_global_load_lds(
      (const __attribute__((address_space(1))) unsigned int*)g,
      (__attribute__((address_space(3))) unsigned int*)l, 16, 0, 0);
}

__device__ __forceinline__ uint32_t lds_u32(void* p) {
  return (uint32_t)(uintptr_t)(__attribute__((address_space(3))) char*)p;
}

template <int OFF>
__device__ __forceinline__ bf16x8 dsr16(uint32_t a) {
  bf16x8 r;
  asm volatile("ds_read_b128 %0, %1 offset:%2" : "=v"(r) : "v"(a), "i"(OFF));
  return r;
}

__global__ __launch_bounds__(512, 2) void gemm256(
    const unsigned short* __restrict__ A,   // [M][K] bf16
    const unsigned short* __restrict__ B,   // [N][K] bf16
    const float* __restrict__ bias,         // [N]
    float* __restrict__ C,                  // [M][N] f32
    int M, int N, int K) {
  __shared__ __align__(1024) char lds[131072];

  const int nwg = (int)gridDim.x;
  int wg = (int)blockIdx.x;
  wg = (wg & 7) * (nwg >> 3) + (wg >> 3);       // bijective: nwg % 8 == 0
  const int ntn = N >> 8;
  const int tm = wg / ntn, tn = wg - tm * ntn;

  const int tid = (int)threadIdx.x;
  const int w = tid >> 6, l = tid & 63;
  const int wr = w >> 2, wc = w & 3;            // wave grid 2(M) x 4(N)
  const int l15 = l & 15;

  // read-side swizzled lane offset within a 1KiB (16row x 64B) subtile
  int laneRd = (l15 << 6) | ((l >> 4) << 4);
  laneRd ^= ((l15 >> 1) & 3) << 4;
  // stage-side: lane l sources global row l>>2, col-slot pre-inverse-swizzled
  const int stRow = l >> 2;
  const int stCol = (((l & 3) ^ ((l >> 3) & 3)) << 4);

  const char* Ag = (const char*)A;
  const char* Bg = (const char*)B;
  const long rowA0 = (long)tm * 256;
  const long rowB0 = (long)tn * 256;
  const long Kb = (long)K;

  const uint32_t lds0  = lds_u32(&lds[0]);
  const uint32_t aBase = lds0 + (uint32_t)(wr * 8192 + laneRd);
  const uint32_t bBase = lds0 + 16384u + (uint32_t)(wc * 4096 + laneRd);

  // stage 2 subtiles (u = w*2, w*2+1) of tile kt_ into buffer cs_
#define STAGE_A(kt_, cs_)                                                     \
  _Pragma("unroll")                                                           \
  for (int i_ = 0; i_ < 2; ++i_) {                                            \
    const int u_ = w * 2 + i_;                                                \
    gload_lds16(Ag + 2 * ((rowA0 + u_ * 16 + stRow) * Kb + (long)(kt_) * 32) + stCol, \
                &lds[(cs_) * 32768 + u_ * 1024]);                             \
  }
#define STAGE_B(kt_, cs_)                                                     \
  _Pragma("unroll")                                                           \
  for (int i_ = 0; i_ < 2; ++i_) {                                            \
    const int u_ = w * 2 + i_;                                                \
    gload_lds16(Bg + 2 * ((rowB0 + u_ * 16 + stRow) * Kb + (long)(kt_) * 32) + stCol, \
                &lds[(cs_) * 32768 + 16384 + u_ * 1024]);                     \
  }

#define MFMA16(base_)                                                         \
  _Pragma("unroll")                                                           \
  for (int mi = 0; mi < 4; ++mi)                                              \
    _Pragma("unroll")                                                         \
    for (int ni = 0; ni < 4; ++ni)                                            \
      acc[(base_) + mi][ni] = __builtin_amdgcn_mfma_f32_16x16x32_bf16(        \
          aq[mi], bq[ni], acc[(base_) + mi][ni], 0, 0, 0);

// One BK=32 tile: c_ = buffer (compile-time 0..3), kt_ = K-tile index,
// vm_ = vmcnt literal at tile end, st_ = stage tile kt_+3 into (c_+3)&3.
#define TILE_BODY(c_, kt_, vm_, st_)                                          \
  {                                                                           \
    const uint32_t aB = aBase + (c_) * 32768u;                                \
    const uint32_t bB = bBase + (c_) * 32768u;                                \
    bf16x8 aq[4], bq[4];                                                      \
    bq[0] = dsr16<0>(bB);    bq[1] = dsr16<1024>(bB);                         \
    bq[2] = dsr16<2048>(bB); bq[3] = dsr16<3072>(bB);                         \
    aq[0] = dsr16<0>(aB);    aq[1] = dsr16<1024>(aB);                         \
    aq[2] = dsr16<2048>(aB); aq[3] = dsr16<3072>(aB);                         \
    if (st_) { STAGE_A((kt_) + 3, ((c_) + 3) & 3) }                           \
    __builtin_amdgcn_s_barrier();                                             \
    asm volatile("s_waitcnt lgkmcnt(0)" ::: "memory");                        \
    __builtin_amdgcn_sched_barrier(0);                                        \
    __builtin_amdgcn_s_setprio(1);                                            \
    MFMA16(0)                                                                 \
    __builtin_amdgcn_s_setprio(0);                                            \
    aq[0] = dsr16<4096>(aB); aq[1] = dsr16<5120>(aB);                         \
    aq[2] = dsr16<6144>(aB); aq[3] = dsr16<7168>(aB);                         \
    if (st_) { STAGE_B((kt_) + 3, ((c_) + 3) & 3) }                           \
    asm volatile("s_waitcnt lgkmcnt(0)" ::: "memory");                        \
    __builtin_amdgcn_sched_barrier(0);                                        \
    __builtin_amdgcn_s_setprio(1);                                            \
    MFMA16(4)                                                                 \
    __builtin_amdgcn_s_setprio(0);                                            \
    asm volatile("s_waitcnt vmcnt(" #vm_ ")" ::: "memory");                   \
    __builtin_amdgcn_sched_barrier(0);                                        \
    __builtin_amdgcn_s_barrier();                                             \
  }

  f32x4 acc[8][4];
#pragma unroll
  for (int i = 0; i < 8; ++i)
#pragma unroll
    for (int j = 0; j < 4; ++j) acc[i][j] = (f32x4){0.f, 0.f, 0.f, 0.f};

  const int NTt = K >> 5;   // 128 K-tiles of BK=32

  // prologue: stage tiles 0,1,2 into buffers 0,1,2 (12 gloads/wave)
  STAGE_A(0, 0) STAGE_B(0, 0)
  STAGE_A(1, 1) STAGE_B(1, 1)
  STAGE_A(2, 2) STAGE_B(2, 2)
  asm volatile("s_waitcnt vmcnt(8)" ::: "memory");   // tile 0's 4 retired
  __builtin_amdgcn_sched_barrier(0);
  __builtin_amdgcn_s_barrier();

  int kt = 0;
  for (; kt + 7 < NTt; kt += 4) {
    TILE_BODY(0, kt,     8, 1)
    TILE_BODY(1, kt + 1, 8, 1)
    TILE_BODY(2, kt + 2, 8, 1)
    TILE_BODY(3, kt + 3, 8, 1)
  }
  // peel: tiles NTt-4 .. NTt-1 (NTt % 4 == 0)
  TILE_BODY(0, kt,     8, 1)   // stages tile NTt-1
  TILE_BODY(1, kt + 1, 4, 0)
  TILE_BODY(2, kt + 2, 0, 0)
  TILE_BODY(3, kt + 3, 0, 0)

  // epilogue: C/D layout col = lane&15, row = (lane>>4)*4 + j
#pragma unroll
  for (int ni = 0; ni < 4; ++ni) {
    const int col = tn * 256 + wc * 64 + ni * 16 + l15;
    const float bv = bias[col];
#pragma unroll
    for (int mi = 0; mi < 8; ++mi) {
      const int r0 = tm * 256 + wr * 128 + mi * 16 + ((l >> 4) << 2);
      f32x4 v = acc[mi][ni];
#pragma unroll
      for (int j = 0; j < 4; ++j)
        C[(size_t)(r0 + j) * N + col] = v[j] + bv;
    }
  }
#undef STAGE_A
#undef STAGE_B
#undef MFMA16
#undef TILE_BODY
}

// ---------------------------------------------------------------------------
extern "C" void kernel_launch(void* const* d_in, const int* in_sizes, int n_in,
                              void* d_out, int out_size, void* d_ws, size_t ws_size,
                              hipStream_t stream) {
  const float* x    = (const float*)d_in[0];
  const float* bias = (const float*)d_in[1];
  const int*   seed = (const int*)d_in[2];
  float* out = (float*)d_out;

  const int K = 4096;                       // IN_FEATURES
  const int N = in_sizes[1];                // OUT_FEATURES (4096)
  const int M = in_sizes[0] / K;            // BATCH*SEQ (8192)

  unsigned short* W  = (unsigned short*)d_ws;
  unsigned short* Xb = W + (size_t)N * K;

  gen_and_cast<<<8192, 256, 0, stream>>>(x, Xb, W, seed, M * K, N * K);

  dim3 grid((M / 256) * (N / 256));
  gemm256<<<grid, 512, 0, stream>>>((const unsigned short*)Xb,
                                    (const unsigned short*)W,
                                    bias, out, M, N, K);
}